// Round 1
// baseline (638.716 us; speedup 1.0000x reference)
//
#include <hip/hip_runtime.h>
#include <hip/hip_bf16.h>

typedef __bf16 bf16x8 __attribute__((ext_vector_type(8)));
typedef float  f32x4  __attribute__((ext_vector_type(4)));

#define HD  128   // hidden dim
#define ROW 256   // 2*HD floats per row

// One block: 512 threads = 8 waves. Each chunk = 128 rows (16 rows per wave).
// W (128x128) is bf16-converted and pre-swizzled into LDS in MFMA-fragment
// order once per block.
//
// KEY CHANGE vs prior version: operands SWAPPED in the mfma —
//   D = Wfrag * Xfrag = (x1 @ W)^T fragment-wise, so the C/D layout
//   (col=lane&15, row=quad*4+r) gives each lane 4 CONSECUTIVE COLUMNS of
//   its OWN row (arow = m0+lane15). Epilogue is pure f32x4, 64B-contiguous
//   per row per instruction. A/B fragment layouts are identical
//   (operand[idx&15], k=(idx>>4)*8+j), so LDS/afrag setup is unchanged.
__global__ __launch_bounds__(512, 8)
void revnet_mfma(const float* __restrict__ x, const float* __restrict__ w,
                 float* __restrict__ out, int num_chunks) {
    // 8 n-tiles * 4 k-steps * 64 lanes * 8 bf16 = 16384 bf16 = 32 KB
    __shared__ __attribute__((aligned(16))) __bf16 ldsB[2048 * 8];

    const int tid    = threadIdx.x;
    const int lane   = tid & 63;
    const int wave   = tid >> 6;
    const int lane15 = lane & 15;
    const int quad   = lane >> 4;

    // ---- fill W fragments into LDS (fragment layout for 16x16x32 bf16) ----
    // slot s = (nt*4 + ks)*64 + sl ; holds W[k0+j][n], j=0..7
    #pragma unroll
    for (int i = 0; i < 4; ++i) {
        int s  = i * 512 + tid;
        int sl = s & 63;
        int t  = s >> 6;
        int ks = t & 3;
        int nt = t >> 2;
        int k0 = ks * 32 + (sl >> 4) * 8;
        int n  = nt * 16 + (sl & 15);
        bf16x8 frag;
        #pragma unroll
        for (int j = 0; j < 8; ++j)
            frag[j] = (__bf16)w[(k0 + j) * HD + n];
        *(bf16x8*)&ldsB[s * 8] = frag;
    }
    __syncthreads();

    for (int c = blockIdx.x; c < num_chunks; c += gridDim.x) {
        const int m0   = c * 128 + wave * 16;
        const int arow = m0 + lane15;
        const float* __restrict__ xr = x   + (size_t)arow * ROW;
        float*       __restrict__ yr = out + (size_t)arow * ROW;

        // A fragments for mfma B-operand: lane holds x1[arow][k=ks*32+quad*8+j]
        bf16x8 afrag[4];
        #pragma unroll
        for (int ks = 0; ks < 4; ++ks) {
            const int k0 = ks * 32 + quad * 8;
            f32x4 v0 = *(const f32x4*)(xr + k0);
            f32x4 v1 = *(const f32x4*)(xr + k0 + 4);
            #pragma unroll
            for (int j = 0; j < 4; ++j) {
                afrag[ks][j]     = (__bf16)v0[j];
                afrag[ks][j + 4] = (__bf16)v1[j];
            }
        }

        f32x4 acc[8];
        #pragma unroll
        for (int nt = 0; nt < 8; ++nt) acc[nt] = (f32x4){0.f, 0.f, 0.f, 0.f};

        // SWAPPED operands: D = W^T-frag * x1^T-frag = h^T layout.
        #pragma unroll
        for (int ks = 0; ks < 4; ++ks) {
            #pragma unroll
            for (int nt = 0; nt < 8; ++nt) {
                bf16x8 bfrag = *(const bf16x8*)&ldsB[((nt * 4 + ks) * 64 + lane) * 8];
                acc[nt] = __builtin_amdgcn_mfma_f32_16x16x32_bf16(
                              bfrag, afrag[ks], acc[nt], 0, 0, 0);
            }
        }

        // ---- epilogue: lane owns row arow; acc[nt][r] = h[arow][nt*16+quad*4+r]
        // y1 passthrough re-reads x1 (L1/L2 hit) so every store is
        // 64B-contiguous per row per instruction.
        #pragma unroll
        for (int nt = 0; nt < 8; ++nt) {
            const int c0 = nt * 16 + quad * 4;
            f32x4 x1v = *(const f32x4*)(xr + c0);
            f32x4 x2v = *(const f32x4*)(xr + HD + c0);
            *(f32x4*)(yr + c0)      = x1v;
            *(f32x4*)(yr + HD + c0) = x2v + acc[nt];
        }
    }
}

extern "C" void kernel_launch(void* const* d_in, const int* in_sizes, int n_in,
                              void* d_out, int out_size, void* d_ws, size_t ws_size,
                              hipStream_t stream) {
    const float* x   = (const float*)d_in[0];
    const float* w   = (const float*)d_in[1];
    float*       out = (float*)d_out;

    const int rows       = out_size / ROW;   // 262144
    const int num_chunks = rows / 128;       // 2048 chunks of 128 rows
    int grid = num_chunks < 1024 ? num_chunks : 1024;   // fully resident: 4 blocks/CU

    revnet_mfma<<<dim3(grid), dim3(512), 0, stream>>>(x, w, out, num_chunks);
}

// Round 2
// 595.599 us; speedup vs baseline: 1.0724x; 1.0724x over previous
//
#include <hip/hip_runtime.h>
#include <hip/hip_bf16.h>

typedef __bf16 bf16x8 __attribute__((ext_vector_type(8)));
typedef float  f32x4  __attribute__((ext_vector_type(4)));

#define HD  128   // hidden dim
#define ROW 256   // 2*HD floats per row

// 384 threads = 6 waves per block; 32 KB LDS -> 5 blocks/CU -> 30 waves/CU (94%).
// Each WAVE independently grid-strides over 16-row tiles (no block-level
// coupling after the one-time W fill), so block size is free to match LDS.
//
// MFMA operands are SWAPPED (D = Wfrag * Xfrag): C/D layout gives each lane
// 4 consecutive columns of its OWN row (arow = m0 + lane15), so the y2
// epilogue is pure f32x4 (64B-contiguous per row per instruction).
// y1 passthrough is stored straight from the fp32 A-fragment load registers
// (exact fp32, zero re-read -> FETCH stays at the 268 MB ideal).
__global__ __launch_bounds__(384, 6)
void revnet_mfma(const float* __restrict__ x, const float* __restrict__ w,
                 float* __restrict__ out, int num_tiles) {
    // 8 n-tiles * 4 k-steps * 64 lanes * 8 bf16 = 16384 bf16 = 32 KB
    __shared__ __attribute__((aligned(16))) __bf16 ldsB[2048 * 8];

    const int tid    = threadIdx.x;
    const int lane   = tid & 63;
    const int wave   = tid >> 6;        // 0..5
    const int lane15 = lane & 15;
    const int quad   = lane >> 4;

    // ---- fill W fragments into LDS (fragment layout for 16x16x32 bf16) ----
    // slot s = (nt*4 + ks)*64 + sl ; holds W[k0+j][n], j=0..7
    for (int s = tid; s < 2048; s += 384) {
        int sl = s & 63;
        int t  = s >> 6;
        int ks = t & 3;
        int nt = t >> 2;
        int k0 = ks * 32 + (sl >> 4) * 8;
        int n  = nt * 16 + (sl & 15);
        bf16x8 frag;
        #pragma unroll
        for (int j = 0; j < 8; ++j)
            frag[j] = (__bf16)w[(k0 + j) * HD + n];
        *(bf16x8*)&ldsB[s * 8] = frag;
    }
    __syncthreads();

    // ---- per-wave grid-stride over 16-row tiles ----
    const int gwave  = blockIdx.x * 6 + wave;
    const int nwaves = gridDim.x * 6;

    for (int t = gwave; t < num_tiles; t += nwaves) {
        const int arow = t * 16 + lane15;
        const float* __restrict__ xr = x   + (size_t)arow * ROW;
        float*       __restrict__ yr = out + (size_t)arow * ROW;

        // A-side fragments (used as mfma B operand): lane holds
        // x1[arow][k = ks*32 + quad*8 + j]; y1 passthrough stored from the
        // same fp32 registers (exact).
        bf16x8 afrag[4];
        #pragma unroll
        for (int ks = 0; ks < 4; ++ks) {
            const int k0 = ks * 32 + quad * 8;
            f32x4 v0 = *(const f32x4*)(xr + k0);
            f32x4 v1 = *(const f32x4*)(xr + k0 + 4);
            *(f32x4*)(yr + k0)     = v0;   // out[:, :128] = x1
            *(f32x4*)(yr + k0 + 4) = v1;
            #pragma unroll
            for (int j = 0; j < 4; ++j) {
                afrag[ks][j]     = (__bf16)v0[j];
                afrag[ks][j + 4] = (__bf16)v1[j];
            }
        }

        f32x4 acc[8];
        #pragma unroll
        for (int nt = 0; nt < 8; ++nt) acc[nt] = (f32x4){0.f, 0.f, 0.f, 0.f};

        // Swapped operands: D = W-frag * x1-frag -> lane owns row arow,
        // cols nt*16 + quad*4 + r.
        #pragma unroll
        for (int ks = 0; ks < 4; ++ks) {
            #pragma unroll
            for (int nt = 0; nt < 8; ++nt) {
                bf16x8 bfrag = *(const bf16x8*)&ldsB[((nt * 4 + ks) * 64 + lane) * 8];
                acc[nt] = __builtin_amdgcn_mfma_f32_16x16x32_bf16(
                              bfrag, afrag[ks], acc[nt], 0, 0, 0);
            }
        }

        // ---- epilogue: y2 = x2 + h, 64B-contiguous per row per instruction ----
        #pragma unroll
        for (int nt = 0; nt < 8; ++nt) {
            const int c0 = nt * 16 + quad * 4;
            f32x4 x2v = *(const f32x4*)(xr + HD + c0);
            *(f32x4*)(yr + HD + c0) = x2v + acc[nt];
        }
    }
}

extern "C" void kernel_launch(void* const* d_in, const int* in_sizes, int n_in,
                              void* d_out, int out_size, void* d_ws, size_t ws_size,
                              hipStream_t stream) {
    const float* x   = (const float*)d_in[0];
    const float* w   = (const float*)d_in[1];
    float*       out = (float*)d_out;

    const int rows      = out_size / ROW;   // 262144
    const int num_tiles = rows / 16;        // 16384 16-row tiles
    // 5 blocks/CU (32 KB LDS each) x 256 CUs = 1280 fully-resident blocks.
    int grid = 1280;

    revnet_mfma<<<dim3(grid), dim3(384), 0, stream>>>(x, w, out, num_tiles);
}

// Round 3
// 531.170 us; speedup vs baseline: 1.2025x; 1.1213x over previous
//
#include <hip/hip_runtime.h>
#include <hip/hip_bf16.h>

typedef __bf16 bf16x8 __attribute__((ext_vector_type(8)));
typedef float  f32x4  __attribute__((ext_vector_type(4)));

#define HD  128   // hidden dim
#define ROW 256   // 2*HD floats per row

// Round-0 proven skeleton: 256 threads = 4 waves, 64-row chunks, block-stride,
// y1 passthrough stored straight from the x1 load registers (FETCH = 268 MB
// exact, no re-reads). Changes vs round 0:
//   (a) swapped-operand MFMA (D = Wfrag * Xfrag) so each lane owns 4
//       consecutive columns of its OWN row -> y2 epilogue is pure f32x4
//       (64B sector-aligned stores instead of scalar 4B scatter);
//   (b) x2 loads hoisted ABOVE the MFMA phase, vectorized in D-layout ->
//       16 dwordx4 loads in flight per wave instead of 8 + a post-MFMA
//       scalar-load latency epoch.
__global__ __launch_bounds__(256, 4)
void revnet_mfma(const float* __restrict__ x, const float* __restrict__ w,
                 float* __restrict__ out, int num_chunks) {
    // 8 n-tiles * 4 k-steps * 64 lanes * 8 bf16 = 16384 bf16 = 32 KB
    __shared__ __attribute__((aligned(16))) __bf16 ldsB[2048 * 8];

    const int tid    = threadIdx.x;
    const int lane   = tid & 63;
    const int wave   = tid >> 6;
    const int lane15 = lane & 15;
    const int quad   = lane >> 4;

    // ---- fill W fragments into LDS (fragment layout for 16x16x32 bf16) ----
    // slot s = (nt*4 + ks)*64 + sl ; holds W[k0+j][n], j=0..7
    #pragma unroll
    for (int i = 0; i < 8; ++i) {
        int s  = i * 256 + tid;
        int sl = s & 63;
        int t  = s >> 6;
        int ks = t & 3;
        int nt = t >> 2;
        int k0 = ks * 32 + (sl >> 4) * 8;
        int n  = nt * 16 + (sl & 15);
        bf16x8 frag;
        #pragma unroll
        for (int j = 0; j < 8; ++j)
            frag[j] = (__bf16)w[(k0 + j) * HD + n];
        *(bf16x8*)&ldsB[s * 8] = frag;
    }
    __syncthreads();

    for (int c = blockIdx.x; c < num_chunks; c += gridDim.x) {
        const int m0   = c * 64 + wave * 16;
        const int arow = m0 + lane15;
        const float* __restrict__ xr = x   + (size_t)arow * ROW;
        float*       __restrict__ yr = out + (size_t)arow * ROW;

        // ---- issue ALL 16 loads first (max memory-level parallelism) ----
        // x1 in fragment layout: lane holds x1[arow][ks*32 + quad*8 + j]
        f32x4 v0[4], v1[4];
        #pragma unroll
        for (int ks = 0; ks < 4; ++ks) {
            const int k0 = ks * 32 + quad * 8;
            v0[ks] = *(const f32x4*)(xr + k0);
            v1[ks] = *(const f32x4*)(xr + k0 + 4);
        }
        // x2 in D-layout (64B sector-aligned per row), used after MFMA.
        f32x4 x2v[8];
        #pragma unroll
        for (int nt = 0; nt < 8; ++nt)
            x2v[nt] = *(const f32x4*)(xr + HD + nt * 16 + quad * 4);

        // ---- y1 passthrough (exact fp32, from load regs) + bf16 cvt ----
        bf16x8 afrag[4];
        #pragma unroll
        for (int ks = 0; ks < 4; ++ks) {
            const int k0 = ks * 32 + quad * 8;
            *(f32x4*)(yr + k0)     = v0[ks];
            *(f32x4*)(yr + k0 + 4) = v1[ks];
            #pragma unroll
            for (int j = 0; j < 4; ++j) {
                afrag[ks][j]     = (__bf16)v0[ks][j];
                afrag[ks][j + 4] = (__bf16)v1[ks][j];
            }
        }

        f32x4 acc[8];
        #pragma unroll
        for (int nt = 0; nt < 8; ++nt) acc[nt] = (f32x4){0.f, 0.f, 0.f, 0.f};

        // Swapped operands: D = W-frag * x1-frag -> lane owns row arow,
        // cols nt*16 + quad*4 + r.
        #pragma unroll
        for (int ks = 0; ks < 4; ++ks) {
            #pragma unroll
            for (int nt = 0; nt < 8; ++nt) {
                bf16x8 bfrag = *(const bf16x8*)&ldsB[((nt * 4 + ks) * 64 + lane) * 8];
                acc[nt] = __builtin_amdgcn_mfma_f32_16x16x32_bf16(
                              bfrag, afrag[ks], acc[nt], 0, 0, 0);
            }
        }

        // ---- epilogue: y2 = x2 + h, 64B-contiguous per row per instruction ----
        #pragma unroll
        for (int nt = 0; nt < 8; ++nt) {
            const int c0 = nt * 16 + quad * 4;
            *(f32x4*)(yr + HD + c0) = x2v[nt] + acc[nt];
        }
    }
}

extern "C" void kernel_launch(void* const* d_in, const int* in_sizes, int n_in,
                              void* d_out, int out_size, void* d_ws, size_t ws_size,
                              hipStream_t stream) {
    const float* x   = (const float*)d_in[0];
    const float* w   = (const float*)d_in[1];
    float*       out = (float*)d_out;

    const int rows       = out_size / ROW;   // 262144
    const int num_chunks = rows / 64;        // 4096 chunks of 64 rows
    // 5 blocks/CU by LDS (32 KB) x 256 CUs = 1280; block-stride covers the rest.
    int grid = num_chunks < 1280 ? num_chunks : 1280;

    revnet_mfma<<<dim3(grid), dim3(256), 0, stream>>>(x, w, out, num_chunks);
}

// Round 4
// 437.227 us; speedup vs baseline: 1.4608x; 1.2149x over previous
//
#include <hip/hip_runtime.h>
#include <hip/hip_bf16.h>

typedef __bf16 bf16x4 __attribute__((ext_vector_type(4)));
typedef __bf16 bf16x8 __attribute__((ext_vector_type(8)));
typedef float  f32x4  __attribute__((ext_vector_type(4)));

#define HD   128
#define ROW  256   // 2*HD floats per row
#define TROW 256   // bytes per row of per-wave transpose buffer (128 bf16, XOR-swizzled)

// Streaming restructure: every global access is a full-wave 1KB CONTIGUOUS
// instruction (64 lanes x f32x4 = one whole row of x or y).
//   load row i  -> lanes 0-31 hold x1, lanes 32-63 hold x2 (kept in regs)
//   x1 -> bf16 -> per-wave private 4KB LDS (XOR swizzle (row&7)<<4) -> MFMA frags
//   MFMA (swapped operands, proven): acc[nt][r] = h[m0+lane15][nt*16+quad*4+r]
//   h -> bf16 -> same LDS buffer -> read back row-major -> single 1KB store/row
//     (lanes 0-31 store x1 exact fp32 passthrough, lanes 32-63 store x2+h)
// Per-wave private buffer => NO barriers in the loop (DS is in-order per wave).
// LDS: 32KB (W) + 4x4KB = 48.75KB -> 3 blocks/CU; grid = 768 fully resident.
// VGPR: r[16](64) + acc(32) + frag/addr ~= 115 <= 128 cap.
__global__ __launch_bounds__(256, 4)
void revnet_mfma(const float* __restrict__ x, const float* __restrict__ w,
                 float* __restrict__ out, int num_chunks) {
    __shared__ __attribute__((aligned(16))) __bf16 ldsW[2048 * 8];      // 32 KB
    __shared__ __attribute__((aligned(16))) __bf16 ldsT[4][16 * 128];   // 4 x 4 KB

    const int tid    = threadIdx.x;
    const int lane   = tid & 63;
    const int wave   = tid >> 6;
    const int lane15 = lane & 15;
    const int quad   = lane >> 4;
    const int l31    = lane & 31;

    // ---- W fragments into LDS (layout proven in rounds 0-3) ----
    // slot s = (nt*4 + ks)*64 + sl ; holds W[k0+j][n], j=0..7
    #pragma unroll
    for (int i = 0; i < 8; ++i) {
        int s  = i * 256 + tid;
        int sl = s & 63;
        int t  = s >> 6;
        int ks = t & 3;
        int nt = t >> 2;
        int k0 = ks * 32 + (sl >> 4) * 8;
        int n  = nt * 16 + (sl & 15);
        bf16x8 frag;
        #pragma unroll
        for (int j = 0; j < 8; ++j)
            frag[j] = (__bf16)w[(k0 + j) * HD + n];
        *(bf16x8*)&ldsW[s * 8] = frag;
    }
    __syncthreads();

    char* T = (char*)&ldsT[wave][0];   // this wave's private transpose buffer

    for (int c = blockIdx.x; c < num_chunks; c += gridDim.x) {
        const int m0 = c * 64 + wave * 16;
        const float* __restrict__ xr = x   + (size_t)m0 * ROW;
        float*       __restrict__ yr = out + (size_t)m0 * ROW;

        // ---- Phase 1: 16 fully-contiguous 1KB row loads ----
        f32x4 r[16];
        #pragma unroll
        for (int i = 0; i < 16; ++i)
            r[i] = *(const f32x4*)(xr + i * ROW + 4 * lane);

        // ---- Phase 2: lanes 0-31 stage x1 as bf16 into swizzled LDS rows ----
        if (lane < 32) {
            #pragma unroll
            for (int i = 0; i < 16; ++i) {
                bf16x4 b;
                b[0] = (__bf16)r[i][0]; b[1] = (__bf16)r[i][1];
                b[2] = (__bf16)r[i][2]; b[3] = (__bf16)r[i][3];
                *(bf16x4*)(T + i * TROW + ((l31 * 8) ^ ((i & 7) << 4))) = b;
            }
        }
        // no barrier: buffer is wave-private; DS ops complete in order per wave

        f32x4 acc[8];
        #pragma unroll
        for (int nt = 0; nt < 8; ++nt) acc[nt] = (f32x4){0.f, 0.f, 0.f, 0.f};

        // ---- Phase 3: MFMA (swapped operands; afrag built per-ks: low VGPR) ----
        #pragma unroll
        for (int ks = 0; ks < 4; ++ks) {
            bf16x8 af = *(const bf16x8*)(T + lane15 * TROW +
                          ((ks * 64 + quad * 16) ^ ((lane15 & 7) << 4)));
            #pragma unroll
            for (int nt = 0; nt < 8; ++nt) {
                bf16x8 bfrag = *(const bf16x8*)&ldsW[((nt * 4 + ks) * 64 + lane) * 8];
                acc[nt] = __builtin_amdgcn_mfma_f32_16x16x32_bf16(
                              bfrag, af, acc[nt], 0, 0, 0);
            }
        }

        // ---- Phase 4: h (D-layout) -> bf16 -> same swizzled LDS rows ----
        #pragma unroll
        for (int nt = 0; nt < 8; ++nt) {
            bf16x4 hb;
            hb[0] = (__bf16)acc[nt][0]; hb[1] = (__bf16)acc[nt][1];
            hb[2] = (__bf16)acc[nt][2]; hb[3] = (__bf16)acc[nt][3];
            *(bf16x4*)(T + lane15 * TROW +
                       ((nt * 32 + quad * 8) ^ ((lane15 & 7) << 4))) = hb;
        }

        // ---- Phase 5: per row: read h row-major, add on high half, 1KB store ----
        #pragma unroll
        for (int i = 0; i < 16; ++i) {
            bf16x4 hb = *(const bf16x4*)(T + i * TROW + ((l31 * 8) ^ ((i & 7) << 4)));
            f32x4 v = r[i];
            if (lane >= 32) {
                v[0] += (float)hb[0]; v[1] += (float)hb[1];
                v[2] += (float)hb[2]; v[3] += (float)hb[3];
            }
            *(f32x4*)(yr + i * ROW + 4 * lane) = v;
        }
    }
}

extern "C" void kernel_launch(void* const* d_in, const int* in_sizes, int n_in,
                              void* d_out, int out_size, void* d_ws, size_t ws_size,
                              hipStream_t stream) {
    const float* x   = (const float*)d_in[0];
    const float* w   = (const float*)d_in[1];
    float*       out = (float*)d_out;

    const int rows       = out_size / ROW;   // 262144
    const int num_chunks = rows / 64;        // 4096 chunks of 64 rows
    // 3 blocks/CU by LDS (49 KB) x 256 CUs = 768 fully-resident blocks.
    int grid = num_chunks < 768 ? num_chunks : 768;

    revnet_mfma<<<dim3(grid), dim3(256), 0, stream>>>(x, w, out, num_chunks);
}